// Round 2
// baseline (524.990 us; speedup 1.0000x reference)
//
#include <hip/hip_runtime.h>
#include <hip/hip_cooperative_groups.h>
#include <math.h>

// PPO fused loss, round 4:
//   pre_coop (cooperative, 256 blocks): segmented-scan (3 phases, elements
//     register-resident across grid.sync), W1/Wh bf16 frag prep, scaled bias.
//   main2: launch_bounds(256,3) for 3 blocks/CU; tanh = fma+exp2+add+rcp+fma
//     with bias folded into pre-scaled b1s; staging packs via cvt_pk;
//     finalize folded in via completion counter. 2 launches total.

namespace cg = cooperative_groups;

typedef __attribute__((ext_vector_type(8))) short short8_t;
typedef __attribute__((ext_vector_type(4))) short short4_t;
typedef __attribute__((ext_vector_type(4))) float float4_t;
typedef __attribute__((ext_vector_type(2))) unsigned uint2_t;
typedef __attribute__((ext_vector_type(4))) unsigned uint4_t;

#define T_TOTAL 262144
#define S_DIM 128
#define H_DIM 1024
#define A_DIM 16
#define GAMMA 0.99f
#define LOG2E2 2.8853900817779268f   // 2*log2(e)

// ws float offsets
#define WS_SUM   0
#define WS_SUMSQ 1
#define WS_TERM  4
#define WS_CNT   5
#define WS_SEGA  8
#define WS_B1S   (WS_SEGA + 2048)       // 1024 floats, inside old SEGA span
#define WS_SEGB  (WS_SEGA + 4096)
#define WS_INC   (WS_SEGB + 4096)
#define WS_ADV   (WS_INC + 4096)        // + T_TOTAL floats
#define WS_W1F   (WS_ADV + T_TOTAL)     // 131072 bf16 = 65536 floats
#define WS_WHF   (WS_W1F + 65536)       // 32768 bf16 = 16384 floats

#define SM_SIZE 32784

__device__ __forceinline__ short f2bf(float f) {
  unsigned u = __float_as_uint(f);
  u += 0x7fffu + ((u >> 16) & 1u);
  return (short)(u >> 16);
}

// packed f32x2 -> bf16x2 (RNE), single instruction
__device__ __forceinline__ unsigned cvt_pk_bf16(float lo, float hi) {
  unsigned r;
  asm("v_cvt_pk_bf16_f32 %0, %1, %2" : "=v"(r) : "v"(lo), "v"(hi));
  return r;
}

// a lanes 32-63 <-> b lanes 0-31 (both registers updated)
__device__ __forceinline__ void permlane32_swap2(unsigned& a, unsigned& b) {
  asm("v_permlane32_swap_b32 %0, %1" : "+v"(a), "+v"(b));
}

// tanh(x + b) where bs = LOG2E2*b pre-scaled: 3 VALU + 2 trans
__device__ __forceinline__ float tanh2(float x, float bs) {
  float a = __builtin_fmaf(x, LOG2E2, bs);
  float e = __builtin_amdgcn_exp2f(a);
  float r = __builtin_amdgcn_rcpf(e + 1.0f);
  return __builtin_fmaf(r, -2.0f, 1.0f);
}

// ---------------------------------------------------------------------------
// pre_coop: 256 blocks x 256 threads, cooperative.
//  phase1: each thread owns 4 scan elements (regs); wave/block affine
//          aggregates -> ws (atomics). Then prep conversions (overlap sync).
//  phase2: block 0 wave 0 suffix-scans 256 block aggregates -> per-block inc.
//  phase3: replay own 4 elements; write ADV; accumulate SUM/SUMSQ.
// Affine convention: chunk map x -> B + A*x (x enters from higher indices);
// compose(L,R) = (aL*aR, bL + aL*bR) with L at lower indices.
// ---------------------------------------------------------------------------
__global__ __launch_bounds__(256, 1) void pre_coop(
    const float* __restrict__ rewards, const int* __restrict__ masks,
    const float* __restrict__ values, const float* __restrict__ W1,
    const float* __restrict__ W_mu, const float* __restrict__ W_lv,
    const float* __restrict__ b1,
    float* __restrict__ ws, short* __restrict__ w1f, short* __restrict__ whf) {
  cg::grid_group grid = cg::this_grid();
  const int tid = threadIdx.x;
  const int b = blockIdx.x;
  const int gid = b * 256 + tid;
  const int lane = tid & 63;
  const int w = tid >> 6;
  __shared__ float wA[4], wB[4], xbs, s1s[4], s2s[4];

  if (b == 0 && tid < 8) atomicExch(&ws[tid], 0.0f);

  // ---- phase 1: own 4 elements -> affine (A,B); wave suffix scan ----
  const float4 r4 = ((const float4*)rewards)[gid];
  const int4 m4i = ((const int4*)masks)[gid];
  const float4 v4 = ((const float4*)values)[gid];
  const float g0 = GAMMA * (float)m4i.x, g1 = GAMMA * (float)m4i.y;
  const float g2 = GAMMA * (float)m4i.z, g3 = GAMMA * (float)m4i.w;
  float A = g3, B = r4.w;
  B = r4.z + g2 * B; A = g2 * A;
  B = r4.y + g1 * B; A = g1 * A;
  B = r4.x + g0 * B; A = g0 * A;
  float SA = A, SB = B;
#pragma unroll
  for (int off = 1; off < 64; off <<= 1) {
    float tA = __shfl_down(SA, off);
    float tB = __shfl_down(SB, off);
    if (lane + off < 64) { SB = SB + SA * tB; SA = SA * tA; }
  }
  float EA = __shfl_down(SA, 1), EB = __shfl_down(SB, 1);
  if (lane == 63) { EA = 1.0f; EB = 0.0f; }
  if (lane == 0) { wA[w] = SA; wB[w] = SB; }
  __syncthreads();
  if (tid == 0) {
    float MA = wA[3], MB = wB[3];
    MB = wB[2] + wA[2] * MB; MA = wA[2] * MA;
    MB = wB[1] + wA[1] * MB; MA = wA[1] * MA;
    MB = wB[0] + wA[0] * MB; MA = wA[0] * MA;
    atomicExch(&ws[WS_SEGA + b], MA);
    atomicExch(&ws[WS_SEGB + b], MB);
  }

  // ---- prep conversions (independent of scan; overlaps sync wait) ----
  {
    // W1 frags: 131072 bf16 elements, 2 per thread
    int id = gid >> 2, e0 = (gid & 3) * 2;
    int ln = id & 63, kf = (id >> 6) & 3, nt = id >> 8;
    int quad = ln >> 4, col = nt * 16 + (ln & 15);
    int kbase = kf * 32 + quad * 8;
    unsigned lo = (unsigned short)f2bf(W1[(size_t)(kbase + e0) * H_DIM + col]);
    unsigned hi = (unsigned short)f2bf(W1[(size_t)(kbase + e0 + 1) * H_DIM + col]);
    *(unsigned*)(w1f + (size_t)id * 8 + e0) = lo | (hi << 16);
  }
  if (gid < 16384) {
    // W_mu|W_lv frags (quad-swizzled k-map): 32768 elements, 2 per thread
    int id = gid >> 2, e0 = (gid & 3) * 2;
    int ln = id & 63, kf = (id >> 6) & 31, nt = id >> 11;
    const float* src = nt ? W_lv : W_mu;
    int quad = ln >> 4, col = ln & 15;
    int hbase = kf * 32 + ((quad >> 1) << 4) + ((quad & 1) << 2);
    int h0 = hbase + ((e0 >> 2) << 3) + (e0 & 3);
    int h1 = hbase + (((e0 + 1) >> 2) << 3) + ((e0 + 1) & 3);
    unsigned lo = (unsigned short)f2bf(src[(size_t)h0 * A_DIM + col]);
    unsigned hi = (unsigned short)f2bf(src[(size_t)h1 * A_DIM + col]);
    *(unsigned*)(whf + (size_t)id * 8 + e0) = lo | (hi << 16);
  }
  if (gid < 1024) ws[WS_B1S + gid] = LOG2E2 * b1[gid];

  grid.sync();

  // ---- phase 2: suffix-scan 256 block aggregates (block 0, wave 0) ----
  if (b == 0 && w == 0) {
    float a0 = atomicAdd(&ws[WS_SEGA + lane * 4 + 0], 0.0f);
    float a1 = atomicAdd(&ws[WS_SEGA + lane * 4 + 1], 0.0f);
    float a2 = atomicAdd(&ws[WS_SEGA + lane * 4 + 2], 0.0f);
    float a3 = atomicAdd(&ws[WS_SEGA + lane * 4 + 3], 0.0f);
    float b0 = atomicAdd(&ws[WS_SEGB + lane * 4 + 0], 0.0f);
    float b1v = atomicAdd(&ws[WS_SEGB + lane * 4 + 1], 0.0f);
    float b2v = atomicAdd(&ws[WS_SEGB + lane * 4 + 2], 0.0f);
    float b3v = atomicAdd(&ws[WS_SEGB + lane * 4 + 3], 0.0f);
    float CA = a3, CB = b3v;
    CB = b2v + a2 * CB; CA = a2 * CA;
    CB = b1v + a1 * CB; CA = a1 * CA;
    CB = b0 + a0 * CB; CA = a0 * CA;
    float PSA = CA, PSB = CB;
#pragma unroll
    for (int off = 1; off < 64; off <<= 1) {
      float tA = __shfl_down(PSA, off);
      float tB = __shfl_down(PSB, off);
      if (lane + off < 64) { PSB = PSB + PSA * tB; PSA = PSA * tA; }
    }
    float XEA = __shfl_down(PSA, 1), XEB = __shfl_down(PSB, 1);
    if (lane == 63) { XEA = 1.0f; XEB = 0.0f; }
    float x = XEB;                       // entering block lane*4+3 (applied to 0)
    atomicExch(&ws[WS_INC + lane * 4 + 3], x);
    x = b3v + a3 * x;
    atomicExch(&ws[WS_INC + lane * 4 + 2], x);
    x = b2v + a2 * x;
    atomicExch(&ws[WS_INC + lane * 4 + 1], x);
    x = b1v + a1 * x;
    atomicExch(&ws[WS_INC + lane * 4 + 0], x);
  }

  grid.sync();

  // ---- phase 3: replay own elements with true entering value ----
  if (tid == 0) xbs = atomicAdd(&ws[WS_INC + b], 0.0f);
  __syncthreads();
  float xw = xbs;
#pragma unroll
  for (int w2 = 3; w2 > 0; --w2)
    if (w2 > w) xw = wB[w2] + wA[w2] * xw;
  float x = EB + EA * xw;
  float x3 = r4.w + g3 * x;
  float x2 = r4.z + g2 * x3;
  float x1 = r4.y + g1 * x2;
  float x0 = r4.x + g0 * x1;
  float4 adv;
  adv.x = x0 - v4.x; adv.y = x1 - v4.y; adv.z = x2 - v4.z; adv.w = x3 - v4.w;
  ((float4*)(ws + WS_ADV))[gid] = adv;
  float s1 = adv.x + adv.y + adv.z + adv.w;
  float s2 = adv.x * adv.x + adv.y * adv.y + adv.z * adv.z + adv.w * adv.w;
#pragma unroll
  for (int m = 1; m < 64; m <<= 1) {
    s1 += __shfl_xor(s1, m);
    s2 += __shfl_xor(s2, m);
  }
  if (lane == 0) { s1s[w] = s1; s2s[w] = s2; }
  __syncthreads();
  if (tid == 0) {
    atomicAdd(&ws[WS_SUM], s1s[0] + s1s[1] + s1s[2] + s1s[3]);
    atomicAdd(&ws[WS_SUMSQ], s2s[0] + s2s[1] + s2s[2] + s2s[3]);
  }
}

// ---------------------------------------------------------------------------
// main2: 64 rows/block, 256 threads (4 waves), 3 blocks/CU target.
// ---------------------------------------------------------------------------
__launch_bounds__(256, 3)
__global__ void main2(const float* __restrict__ states,
                      const float* __restrict__ actions,
                      const float* __restrict__ beta,
                      const float* __restrict__ bmug,
                      const float* __restrict__ blvg,
                      const short* __restrict__ W1f,
                      const short* __restrict__ Whf,
                      float* __restrict__ ws,
                      float* __restrict__ out) {
  __shared__ __align__(16) unsigned char smem[SM_SIZE];
  short* Ab = (short*)smem;

  const int tid = threadIdx.x;
  const int lane = tid & 63;
  const int w = tid >> 6;
  const int quad = lane >> 4;
  const int t0 = blockIdx.x * 64;

  // ---- stage states (64x128 fp32) -> bf16 fragments in LDS ----
  {
    const float4* src = (const float4*)(states + (size_t)t0 * S_DIM);
#pragma unroll
    for (int i = 0; i < 8; ++i) {
      int f = tid + i * 256;
      float4 v = src[f];
      int row = f >> 5, kq = f & 31;
      int rt = row >> 4, rr = row & 15;
      int k = kq * 4, kf = k >> 5, qd = (k >> 3) & 3, j0 = k & 7;
      uint2_t pk2;
      pk2[0] = cvt_pk_bf16(v.x, v.y);
      pk2[1] = cvt_pk_bf16(v.z, v.w);
      *(uint2_t*)(Ab + (((rt * 4 + kf) * 64 + qd * 16 + rr) << 3) + j0) = pk2;
    }
  }
  __syncthreads();

  // states fragments -> registers (t at lane&15, k at quad*8+e)
  short8_t sfrag[4][4];
#pragma unroll
  for (int rt = 0; rt < 4; ++rt)
#pragma unroll
    for (int kf = 0; kf < 4; ++kf)
      sfrag[rt][kf] = *((const short8_t*)Ab + (rt * 4 + kf) * 64 + lane);

  float4_t acc2[4][2];
#pragma unroll
  for (int rt = 0; rt < 4; ++rt) {
    acc2[rt][0] = (float4_t){0.f, 0.f, 0.f, 0.f};
    acc2[rt][1] = (float4_t){0.f, 0.f, 0.f, 0.f};
  }
  const float4_t zz = (float4_t){0.f, 0.f, 0.f, 0.f};
  const float* b1s = ws + WS_B1S;

  for (int kk = 0; kk < 8; ++kk) {
    const int nt1 = w * 16 + kk * 2;          // wave's H-tile pair
    const short8_t* w1p = (const short8_t*)W1f + nt1 * 256 + lane;
    short8_t wf0[4], wf1[4];
#pragma unroll
    for (int kf = 0; kf < 4; ++kf) {
      wf0[kf] = w1p[kf * 64];
      wf1[kf] = w1p[256 + kf * 64];
    }
    const float4 b1a = *(const float4*)(b1s + nt1 * 16 + quad * 4);
    const float4 b1b = *(const float4*)(b1s + nt1 * 16 + 16 + quad * 4);
    const int kf2 = w * 8 + kk;               // GEMM2 K-chunk
    const short8_t* whp = (const short8_t*)Whf + kf2 * 64 + lane;
    const short8_t wmu = whp[0];
    const short8_t wlv = whp[2048];           // nt=1 block (32*64 frags)
#pragma unroll
    for (int rt = 0; rt < 4; ++rt) {
      // GEMM1 (swapped): C1 = h^T tiles; bias applied inside tanh2
      float4_t c0 = zz;
      float4_t c1 = zz;
#pragma unroll
      for (int kf = 0; kf < 4; ++kf) {
        c0 = __builtin_amdgcn_mfma_f32_16x16x32_bf16(wf0[kf], sfrag[rt][kf], c0, 0, 0, 0);
        c1 = __builtin_amdgcn_mfma_f32_16x16x32_bf16(wf1[kf], sfrag[rt][kf], c1, 0, 0, 0);
      }
      // tanh + pack + cross-quad repack into GEMM2 B-fragment
      unsigned p00 = cvt_pk_bf16(tanh2(c0[0], b1a.x), tanh2(c0[1], b1a.y));
      unsigned p01 = cvt_pk_bf16(tanh2(c0[2], b1a.z), tanh2(c0[3], b1a.w));
      unsigned p10 = cvt_pk_bf16(tanh2(c1[0], b1b.x), tanh2(c1[1], b1b.y));
      unsigned p11 = cvt_pk_bf16(tanh2(c1[2], b1b.z), tanh2(c1[3], b1b.w));
      permlane32_swap2(p00, p10);   // p00 = low halves, p10 = high halves
      permlane32_swap2(p01, p11);
      uint4_t u = (uint4_t){p00, p01, p10, p11};
      short8_t b2 = __builtin_bit_cast(short8_t, u);
      acc2[rt][0] = __builtin_amdgcn_mfma_f32_16x16x32_bf16(wmu, b2, acc2[rt][0], 0, 0, 0);
      acc2[rt][1] = __builtin_amdgcn_mfma_f32_16x16x32_bf16(wlv, b2, acc2[rt][1], 0, 0, 0);
    }
  }

  // ---- cross-wave reduce of head partials (overlays staging region) ----
  __syncthreads();
  float* red = (float*)smem;
  float* lds_term = (float*)(smem + 32768);
#pragma unroll
  for (int rt = 0; rt < 4; ++rt)
#pragma unroll
    for (int nt = 0; nt < 2; ++nt)
      *(float4_t*)(red + ((((w * 4 + rt) * 2 + nt) * 64 + lane) << 2)) = acc2[rt][nt];
  __syncthreads();

  // stats (folded): mean / istd from pre_coop's SUM/SUMSQ
  const float s1 = ws[WS_SUM], s2 = ws[WS_SUMSQ];
  const float n = (float)T_TOTAL;
  const float mean = s1 / n;
  float var = (s2 - s1 * s1 / n) / (n - 1.0f);
  var = fmaxf(var, 0.0f);
  const float istd = 1.0f / (sqrtf(var) + 1e-7f);

  // epilogue: wave w handles row-tile rt = w; C2 col = t at lane&15,
  // row = a at quad*4+reg
  const int rt = w;
  const int tcol = lane & 15;
  const int t = t0 + rt * 16 + tcol;
  const float4 bmu4 = *(const float4*)(bmug + quad * 4);
  const float4 blv4 = *(const float4*)(blvg + quad * 4);
  float m0 = bmu4.x, m1 = bmu4.y, m2 = bmu4.z, m3 = bmu4.w;
  float l0 = blv4.x, l1 = blv4.y, l2 = blv4.z, l3 = blv4.w;
  const float4_t* rp = (const float4_t*)red;
#pragma unroll
  for (int wv = 0; wv < 4; ++wv) {
    float4_t mv = rp[((wv * 4 + rt) * 2 + 0) * 64 + lane];
    float4_t lvv = rp[((wv * 4 + rt) * 2 + 1) * 64 + lane];
    m0 += mv[0]; m1 += mv[1]; m2 += mv[2]; m3 += mv[3];
    l0 += lvv[0]; l1 += lvv[1]; l2 += lvv[2]; l3 += lvv[3];
  }
  const float4 av = *(const float4*)(actions + (size_t)t * A_DIM + quad * 4);
  const float4 bv = *(const float4*)(beta + (size_t)t * A_DIM + quad * 4);
  float d = 0.0f;
  {
    float isd, z;
    isd = __expf(-0.5f * l0); z = (av.x - m0) * isd;
    d += -0.5f * z * z - 0.5f * l0 - 0.9189385332046727f - bv.x;
    isd = __expf(-0.5f * l1); z = (av.y - m1) * isd;
    d += -0.5f * z * z - 0.5f * l1 - 0.9189385332046727f - bv.y;
    isd = __expf(-0.5f * l2); z = (av.z - m2) * isd;
    d += -0.5f * z * z - 0.5f * l2 - 0.9189385332046727f - bv.z;
    isd = __expf(-0.5f * l3); z = (av.w - m3) * isd;
    d += -0.5f * z * z - 0.5f * l3 - 0.9189385332046727f - bv.w;
  }
  d += __shfl_xor(d, 16);
  d += __shfl_xor(d, 32);
  float term = 0.0f;
  if (quad == 0) {
    float ratio = __expf(d);
    float ah = (ws[WS_ADV + t] - mean) * istd;
    float rc = fminf(fmaxf(ratio, 0.8f), 1.2f);
    term = fminf(ratio * ah, rc * ah);
  }
  term += __shfl_xor(term, 1);
  term += __shfl_xor(term, 2);
  term += __shfl_xor(term, 4);
  term += __shfl_xor(term, 8);
  if (lane == 0) lds_term[w] = term;
  __syncthreads();
  if (tid == 0) {
    atomicAdd(&ws[WS_TERM], lds_term[0] + lds_term[1] + lds_term[2] + lds_term[3]);
    __threadfence();
    unsigned old = atomicAdd((unsigned*)ws + WS_CNT, 1u);
    if (old == (unsigned)(gridDim.x - 1)) {
      float termv = atomicAdd(&ws[WS_TERM], 0.0f);
      out[0] = ws[WS_SUMSQ] / n - termv / n;
    }
  }
}

extern "C" void kernel_launch(void* const* d_in, const int* in_sizes, int n_in,
                              void* d_out, int out_size, void* d_ws, size_t ws_size,
                              hipStream_t stream) {
  const float* states  = (const float*)d_in[0];
  const float* actions = (const float*)d_in[1];
  const float* rewards = (const float*)d_in[2];
  const float* values  = (const float*)d_in[3];
  const float* beta    = (const float*)d_in[4];
  const float* W1      = (const float*)d_in[5];
  const float* b1      = (const float*)d_in[6];
  const float* W_mu    = (const float*)d_in[7];
  const float* b_mu    = (const float*)d_in[8];
  const float* W_lv    = (const float*)d_in[9];
  const float* b_lv    = (const float*)d_in[10];
  const int*   masks   = (const int*)d_in[11];
  float* ws = (float*)d_ws;
  float* out = (float*)d_out;
  short* w1f = (short*)(ws + WS_W1F);
  short* whf = (short*)(ws + WS_WHF);

  void* args[] = {(void*)&rewards, (void*)&masks, (void*)&values,
                  (void*)&W1, (void*)&W_mu, (void*)&W_lv, (void*)&b1,
                  (void*)&ws, (void*)&w1f, (void*)&whf};
  hipLaunchCooperativeKernel((void*)pre_coop, dim3(256), dim3(256), args, 0, stream);
  hipLaunchKernelGGL(main2, dim3(T_TOTAL / 64), dim3(256), 0, stream,
                     states, actions, beta, b_mu, b_lv, w1f, whf, ws, out);
}

// Round 3
// 326.939 us; speedup vs baseline: 1.6058x; 1.6058x over previous
//
#include <hip/hip_runtime.h>
#include <math.h>

// PPO fused loss, round 5 = round-3 structure (known-good 391us) + 3 targeted
// main2 changes:
//   (1) two-round cross-wave reduce -> LDS 33KB -> 16.4KB (occupancy lever)
//   (2) lean tanh: bias pre-scaled b1s = 2*log2e*b1 (own __restrict__ ptr),
//       tanh = fma + exp2 + add + rcp + fma
//   (3) cvt_pk_bf16 staging packs
// Reverted from round 4: cooperative pre-kernel, threadfence finalize fold,
// launch_bounds(256,3). Aux chain identical to round 3.

typedef __attribute__((ext_vector_type(8))) short short8_t;
typedef __attribute__((ext_vector_type(4))) short short4_t;
typedef __attribute__((ext_vector_type(4))) float float4_t;
typedef __attribute__((ext_vector_type(2))) unsigned uint2_t;
typedef __attribute__((ext_vector_type(4))) unsigned uint4_t;

#define T_TOTAL 262144
#define S_DIM 128
#define H_DIM 1024
#define A_DIM 16
#define GAMMA 0.99f
#define LOG2E2 2.8853900817779268f   // 2*log2(e)
#define SEG_LEN 64
#define NSEG 4096
#define GRP 16
#define NGRP 256

// ws float offsets
#define WS_SUM   0
#define WS_SUMSQ 1
#define WS_TERM  4
#define WS_SEGA  8
#define WS_SEGB  (WS_SEGA + NSEG)
#define WS_INC   (WS_SEGB + NSEG)
#define WS_ADV   (WS_INC + NSEG)            // + T_TOTAL floats
#define WS_W1F   (WS_ADV + T_TOTAL)         // 131072 bf16 = 65536 floats
#define WS_WHF   (WS_W1F + 65536)           // 32768 bf16 = 16384 floats
#define WS_B1S   (WS_WHF + 16384)           // 1024 floats (pre-scaled bias)

// LDS: staging 16 KB overlaid by 16 KB two-round reduce buffer + term
#define SM_SIZE 16400

__device__ __forceinline__ short f2bf(float f) {
  unsigned u = __float_as_uint(f);
  u += 0x7fffu + ((u >> 16) & 1u);
  return (short)(u >> 16);
}

// packed f32x2 -> bf16x2 (RNE), single instruction
__device__ __forceinline__ unsigned cvt_pk_bf16(float lo, float hi) {
  unsigned r;
  asm("v_cvt_pk_bf16_f32 %0, %1, %2" : "=v"(r) : "v"(lo), "v"(hi));
  return r;
}

// a lanes 32-63 <-> b lanes 0-31 (both registers updated)
__device__ __forceinline__ void permlane32_swap2(unsigned& a, unsigned& b) {
  asm("v_permlane32_swap_b32 %0, %1" : "+v"(a), "+v"(b));
}

// tanh(x + b) where bs = LOG2E2*b pre-scaled: 3 VALU + 2 trans
__device__ __forceinline__ float tanh2(float x, float bs) {
  float a = __builtin_fmaf(x, LOG2E2, bs);
  float e = __builtin_amdgcn_exp2f(a);
  float r = __builtin_amdgcn_rcpf(e + 1.0f);
  return __builtin_fmaf(r, -2.0f, 1.0f);
}

// ---------------------------------------------------------------------------
// prep_all: blocks 0-63  : W1 -> bf16 frags [nt(64)][kf(4)][lane][e(8)]
//           blocks 64-79 : W_mu|W_lv -> frags with quad-swizzled k-map
//           blocks 80-95 : scan pass 1 (per-segment affine reduce)
//           block  96    : zero accumulators + pre-scale b1
// ---------------------------------------------------------------------------
__global__ void prep_all(const float* __restrict__ W1,
                         const float* __restrict__ W_mu,
                         const float* __restrict__ W_lv,
                         const float* __restrict__ b1,
                         const float* __restrict__ rewards,
                         const int* __restrict__ masks,
                         float* __restrict__ ws,
                         short* __restrict__ w1f,
                         short* __restrict__ whf) {
  const int blk = blockIdx.x;
  if (blk < 64) {
    int id = blk * 256 + threadIdx.x;        // 0..16383
    int lane = id & 63;
    int kf = (id >> 6) & 3;
    int nt = id >> 8;
    int quad = lane >> 4, col = nt * 16 + (lane & 15);
    int kbase = kf * 32 + quad * 8;
#pragma unroll
    for (int e = 0; e < 8; ++e)
      w1f[(size_t)id * 8 + e] = f2bf(W1[(size_t)(kbase + e) * H_DIM + col]);
  } else if (blk < 80) {
    int id = (blk - 64) * 256 + threadIdx.x; // 0..4095
    int lane = id & 63;
    int kf = (id >> 6) & 31;
    int nt = id >> 11;
    const float* src = nt ? W_lv : W_mu;
    int quad = lane >> 4, col = lane & 15;
    // quad-swizzled k-map matching the permlane32_swap repack at runtime:
    // H(q,e) = (q>>1)*16 + (q&1)*4 + (e>>2)*8 + (e&3)
    int hbase = kf * 32 + ((quad >> 1) << 4) + ((quad & 1) << 2);
#pragma unroll
    for (int e = 0; e < 8; ++e) {
      int hh = hbase + ((e >> 2) << 3) + (e & 3);
      whf[(size_t)id * 8 + e] = f2bf(src[(size_t)hh * A_DIM + col]);
    }
  } else if (blk < 96) {
    int g = (blk - 80) * 256 + threadIdx.x;  // 0..4095 segments
    int lo = g * SEG_LEN;
    const float4* r4 = (const float4*)(rewards + lo);
    const int4* m4 = (const int4*)(masks + lo);
    float a = 1.0f, b = 0.0f;
#pragma unroll 4
    for (int c = 15; c >= 0; --c) {
      float4 r = r4[c]; int4 mm = m4[c];
      float gi;
      gi = GAMMA * (float)mm.w; b = r.w + gi * b; a = gi * a;
      gi = GAMMA * (float)mm.z; b = r.z + gi * b; a = gi * a;
      gi = GAMMA * (float)mm.y; b = r.y + gi * b; a = gi * a;
      gi = GAMMA * (float)mm.x; b = r.x + gi * b; a = gi * a;
    }
    ws[WS_SEGA + g] = a;
    ws[WS_SEGB + g] = b;
  } else {
    if (threadIdx.x < 8) ws[threadIdx.x] = 0.0f;
    int base = threadIdx.x * 4;
    float4 bv = *(const float4*)(b1 + base);
    float4 o;
    o.x = LOG2E2 * bv.x; o.y = LOG2E2 * bv.y;
    o.z = LOG2E2 * bv.z; o.w = LOG2E2 * bv.w;
    *(float4*)(ws + WS_B1S + base) = o;
  }
}

__global__ void scan_pass2(float* __restrict__ ws) {
  __shared__ float gA[NGRP], gB[NGRP], ginc[NGRP];
  int t = threadIdx.x;
  int lo = t * GRP, hi = lo + GRP - 1;
  float A = 1.0f, B = 0.0f;
  for (int s = hi; s >= lo; --s) {
    float as = ws[WS_SEGA + s], bs = ws[WS_SEGB + s];
    B = bs + as * B;
    A = as * A;
  }
  gA[t] = A; gB[t] = B;
  __syncthreads();
  if (t == 0) {
    float x = 0.0f;
    ginc[NGRP - 1] = 0.0f;
    for (int g = NGRP - 1; g >= 1; --g) {
      x = gB[g] + gA[g] * x;
      ginc[g - 1] = x;
    }
  }
  __syncthreads();
  float x = ginc[t];
  for (int s = hi; s >= lo; --s) {
    ws[WS_INC + s] = x;
    x = ws[WS_SEGB + s] + ws[WS_SEGA + s] * x;
  }
}

__global__ void scan_pass3(const float* __restrict__ rewards,
                           const int* __restrict__ masks,
                           const float* __restrict__ values,
                           float* __restrict__ ws) {
  int g = blockIdx.x * blockDim.x + threadIdx.x;
  int lo = g * SEG_LEN;
  float x = ws[WS_INC + g];
  const float4* r4 = (const float4*)(rewards + lo);
  const int4* m4 = (const int4*)(masks + lo);
  const float4* v4 = (const float4*)(values + lo);
  float4* adv4 = (float4*)(ws + WS_ADV + lo);
  float s1 = 0.0f, s2 = 0.0f;
#pragma unroll 4
  for (int c = 15; c >= 0; --c) {
    float4 r = r4[c]; int4 mm = m4[c]; float4 v = v4[c];
    float gi;
    gi = GAMMA * (float)mm.w; x = r.w + gi * x; float aw = x - v.w;
    gi = GAMMA * (float)mm.z; x = r.z + gi * x; float az = x - v.z;
    gi = GAMMA * (float)mm.y; x = r.y + gi * x; float ay = x - v.y;
    gi = GAMMA * (float)mm.x; x = r.x + gi * x; float ax = x - v.x;
    float4 o; o.x = ax; o.y = ay; o.z = az; o.w = aw;
    adv4[c] = o;
    s1 += ax + ay + az + aw;
    s2 += ax * ax + ay * ay + az * az + aw * aw;
  }
  for (int m = 1; m < 64; m <<= 1) {
    s1 += __shfl_xor(s1, m);
    s2 += __shfl_xor(s2, m);
  }
  if ((threadIdx.x & 63) == 0) {
    atomicAdd(&ws[WS_SUM], s1);
    atomicAdd(&ws[WS_SUMSQ], s2);
  }
}

// ---------------------------------------------------------------------------
// main2: 64 rows/block, 256 threads (4 waves). Wave w owns H in
// [w*256,(w+1)*256) (GEMM2 K-split); two-round cross-wave reduce (16 KB LDS).
// ---------------------------------------------------------------------------
__launch_bounds__(256, 2)
__global__ void main2(const float* __restrict__ states,
                      const float* __restrict__ actions,
                      const float* __restrict__ beta,
                      const float* __restrict__ b1s,
                      const float* __restrict__ bmug,
                      const float* __restrict__ blvg,
                      const short* __restrict__ W1f,
                      const short* __restrict__ Whf,
                      float* __restrict__ ws) {
  __shared__ __align__(16) unsigned char smem[SM_SIZE];
  short* Ab = (short*)smem;

  const int tid = threadIdx.x;
  const int lane = tid & 63;
  const int w = tid >> 6;
  const int quad = lane >> 4;
  const int t0 = blockIdx.x * 64;

  // ---- stage states (64x128 fp32) -> bf16 fragments in LDS ----
  {
    const float4* src = (const float4*)(states + (size_t)t0 * S_DIM);
#pragma unroll
    for (int i = 0; i < 8; ++i) {
      int f = tid + i * 256;
      float4 v = src[f];
      int row = f >> 5, kq = f & 31;
      int rt = row >> 4, rr = row & 15;
      int k = kq * 4, kf = k >> 5, qd = (k >> 3) & 3, j0 = k & 7;
      uint2_t pk2;
      pk2[0] = cvt_pk_bf16(v.x, v.y);
      pk2[1] = cvt_pk_bf16(v.z, v.w);
      *(uint2_t*)(Ab + (((rt * 4 + kf) * 64 + qd * 16 + rr) << 3) + j0) = pk2;
    }
  }
  __syncthreads();

  // states fragments -> registers (t at lane&15, k at quad*8+e)
  short8_t sfrag[4][4];
#pragma unroll
  for (int rt = 0; rt < 4; ++rt)
#pragma unroll
    for (int kf = 0; kf < 4; ++kf)
      sfrag[rt][kf] = *((const short8_t*)Ab + (rt * 4 + kf) * 64 + lane);

  float4_t acc2[4][2];
#pragma unroll
  for (int rt = 0; rt < 4; ++rt) {
    acc2[rt][0] = (float4_t){0.f, 0.f, 0.f, 0.f};
    acc2[rt][1] = (float4_t){0.f, 0.f, 0.f, 0.f};
  }
  const float4_t zz = (float4_t){0.f, 0.f, 0.f, 0.f};

  for (int kk = 0; kk < 8; ++kk) {
    const int nt1 = w * 16 + kk * 2;          // wave's H-tile pair
    const short8_t* w1p = (const short8_t*)W1f + nt1 * 256 + lane;
    short8_t wf0[4], wf1[4];
#pragma unroll
    for (int kf = 0; kf < 4; ++kf) {
      wf0[kf] = w1p[kf * 64];
      wf1[kf] = w1p[256 + kf * 64];
    }
    const float4 b1a = *(const float4*)(b1s + nt1 * 16 + quad * 4);
    const float4 b1b = *(const float4*)(b1s + nt1 * 16 + 16 + quad * 4);
    const int kf2 = w * 8 + kk;               // GEMM2 K-chunk
    const short8_t* whp = (const short8_t*)Whf + kf2 * 64 + lane;
    const short8_t wmu = whp[0];
    const short8_t wlv = whp[2048];           // nt=1 block (32*64 frags)
#pragma unroll
    for (int rt = 0; rt < 4; ++rt) {
      // GEMM1 (swapped): C1 = h^T tiles; bias applied inside tanh2
      float4_t c0 = zz;
      float4_t c1 = zz;
#pragma unroll
      for (int kf = 0; kf < 4; ++kf) {
        c0 = __builtin_amdgcn_mfma_f32_16x16x32_bf16(wf0[kf], sfrag[rt][kf], c0, 0, 0, 0);
        c1 = __builtin_amdgcn_mfma_f32_16x16x32_bf16(wf1[kf], sfrag[rt][kf], c1, 0, 0, 0);
      }
      // tanh + pack + cross-quad repack into GEMM2 B-fragment
      unsigned p00 = cvt_pk_bf16(tanh2(c0[0], b1a.x), tanh2(c0[1], b1a.y));
      unsigned p01 = cvt_pk_bf16(tanh2(c0[2], b1a.z), tanh2(c0[3], b1a.w));
      unsigned p10 = cvt_pk_bf16(tanh2(c1[0], b1b.x), tanh2(c1[1], b1b.y));
      unsigned p11 = cvt_pk_bf16(tanh2(c1[2], b1b.z), tanh2(c1[3], b1b.w));
      permlane32_swap2(p00, p10);   // p00 = low halves, p10 = high halves
      permlane32_swap2(p01, p11);
      uint4_t u = (uint4_t){p00, p01, p10, p11};
      short8_t b2 = __builtin_bit_cast(short8_t, u);
      acc2[rt][0] = __builtin_amdgcn_mfma_f32_16x16x32_bf16(wmu, b2, acc2[rt][0], 0, 0, 0);
      acc2[rt][1] = __builtin_amdgcn_mfma_f32_16x16x32_bf16(wlv, b2, acc2[rt][1], 0, 0, 0);
    }
  }

  // ---- two-round cross-wave reduce in 16 KB (overlays staging) ----
  // round 1: waves 0,1 write; round 2: waves 2,3 read-add-write in place.
  __syncthreads();
  float* red = (float*)smem;
  float* lds_term = (float*)(smem + 16384);
  if (w < 2) {
#pragma unroll
    for (int rt = 0; rt < 4; ++rt)
#pragma unroll
      for (int nt = 0; nt < 2; ++nt)
        *(float4_t*)(red + ((((w & 1) * 8 + rt * 2 + nt) * 64 + lane) << 2)) = acc2[rt][nt];
  }
  __syncthreads();
  if (w >= 2) {
#pragma unroll
    for (int rt = 0; rt < 4; ++rt)
#pragma unroll
      for (int nt = 0; nt < 2; ++nt) {
        float* p = red + ((((w & 1) * 8 + rt * 2 + nt) * 64 + lane) << 2);
        float4_t v = *(float4_t*)p;
        v += acc2[rt][nt];
        *(float4_t*)p = v;
      }
  }
  __syncthreads();

  // stats (folded): mean / istd from SUM/SUMSQ
  const float s1 = ws[WS_SUM], s2 = ws[WS_SUMSQ];
  const float n = (float)T_TOTAL;
  const float mean = s1 / n;
  float var = (s2 - s1 * s1 / n) / (n - 1.0f);
  var = fmaxf(var, 0.0f);
  const float istd = 1.0f / (sqrtf(var) + 1e-7f);

  // epilogue: wave w handles row-tile rt = w; C2 col = t at lane&15,
  // row = a at quad*4+reg
  const int rt = w;
  const int tcol = lane & 15;
  const int t = t0 + rt * 16 + tcol;
  const float4 bmu4 = *(const float4*)(bmug + quad * 4);
  const float4 blv4 = *(const float4*)(blvg + quad * 4);
  float m0 = bmu4.x, m1 = bmu4.y, m2 = bmu4.z, m3 = bmu4.w;
  float l0 = blv4.x, l1 = blv4.y, l2 = blv4.z, l3 = blv4.w;
  const float4_t* rp = (const float4_t*)red;
#pragma unroll
  for (int r = 0; r < 2; ++r) {
    float4_t mv = rp[(r * 8 + rt * 2 + 0) * 64 + lane];
    float4_t lvv = rp[(r * 8 + rt * 2 + 1) * 64 + lane];
    m0 += mv[0]; m1 += mv[1]; m2 += mv[2]; m3 += mv[3];
    l0 += lvv[0]; l1 += lvv[1]; l2 += lvv[2]; l3 += lvv[3];
  }
  const float4 av = *(const float4*)(actions + (size_t)t * A_DIM + quad * 4);
  const float4 bv = *(const float4*)(beta + (size_t)t * A_DIM + quad * 4);
  float d = 0.0f;
  {
    float isd, z;
    isd = __expf(-0.5f * l0); z = (av.x - m0) * isd;
    d += -0.5f * z * z - 0.5f * l0 - 0.9189385332046727f - bv.x;
    isd = __expf(-0.5f * l1); z = (av.y - m1) * isd;
    d += -0.5f * z * z - 0.5f * l1 - 0.9189385332046727f - bv.y;
    isd = __expf(-0.5f * l2); z = (av.z - m2) * isd;
    d += -0.5f * z * z - 0.5f * l2 - 0.9189385332046727f - bv.z;
    isd = __expf(-0.5f * l3); z = (av.w - m3) * isd;
    d += -0.5f * z * z - 0.5f * l3 - 0.9189385332046727f - bv.w;
  }
  d += __shfl_xor(d, 16);
  d += __shfl_xor(d, 32);
  float term = 0.0f;
  if (quad == 0) {
    float ratio = __expf(d);
    float ah = (ws[WS_ADV + t] - mean) * istd;
    float rc = fminf(fmaxf(ratio, 0.8f), 1.2f);
    term = fminf(ratio * ah, rc * ah);
  }
  term += __shfl_xor(term, 1);
  term += __shfl_xor(term, 2);
  term += __shfl_xor(term, 4);
  term += __shfl_xor(term, 8);
  if (lane == 0) lds_term[w] = term;
  __syncthreads();
  if (tid == 0)
    atomicAdd(&ws[WS_TERM], lds_term[0] + lds_term[1] + lds_term[2] + lds_term[3]);
}

__global__ void finalize(const float* __restrict__ ws, float* __restrict__ out) {
  if (threadIdx.x == 0) {
    float n = (float)T_TOTAL;
    out[0] = ws[WS_SUMSQ] / n - ws[WS_TERM] / n;
  }
}

extern "C" void kernel_launch(void* const* d_in, const int* in_sizes, int n_in,
                              void* d_out, int out_size, void* d_ws, size_t ws_size,
                              hipStream_t stream) {
  const float* states  = (const float*)d_in[0];
  const float* actions = (const float*)d_in[1];
  const float* rewards = (const float*)d_in[2];
  const float* values  = (const float*)d_in[3];
  const float* beta    = (const float*)d_in[4];
  const float* W1      = (const float*)d_in[5];
  const float* b1      = (const float*)d_in[6];
  const float* W_mu    = (const float*)d_in[7];
  const float* b_mu    = (const float*)d_in[8];
  const float* W_lv    = (const float*)d_in[9];
  const float* b_lv    = (const float*)d_in[10];
  const int*   masks   = (const int*)d_in[11];
  float* ws = (float*)d_ws;
  float* out = (float*)d_out;
  short* w1f = (short*)(ws + WS_W1F);
  short* whf = (short*)(ws + WS_WHF);
  const float* b1s = ws + WS_B1S;

  hipLaunchKernelGGL(prep_all, dim3(97), dim3(256), 0, stream,
                     W1, W_mu, W_lv, b1, rewards, masks, ws, w1f, whf);
  hipLaunchKernelGGL(scan_pass2, dim3(1), dim3(NGRP), 0, stream, ws);
  hipLaunchKernelGGL(scan_pass3, dim3(NSEG / 256), dim3(256), 0, stream,
                     rewards, masks, values, ws);
  hipLaunchKernelGGL(main2, dim3(T_TOTAL / 64), dim3(256), 0, stream,
                     states, actions, beta, b1s, b_mu, b_lv, w1f, whf, ws);
  hipLaunchKernelGGL(finalize, dim3(1), dim3(64), 0, stream, ws, out);
}